// Round 8
// baseline (1113.592 us; speedup 1.0000x reference)
//
#include <hip/hip_runtime.h>
#include <hip/hip_bf16.h>
#include <stdint.h>

#define H 256
#define W 512
#define NCG 18                     // 144/8 channel groups
#define AW 520                     // padded cols: x in [-2, 517]
#define AH 258                     // padded rows: y in [-2, 255]
#define XB 16                      // bytes per pixel per ci-group (8 bf16)
#define ROWB (AW*XB)               // 8320 B
#define CGB (AH*ROWB)              // 2,146,560 B per ci-group plane
#define ACTB ((size_t)NCG*(size_t)CGB)   // 38,638,080 B per activation buffer
#define KG 236                     // kgroups of 8 (13*18=234 real + 2 zero pad)
#define NCHUNK 59                  // K chunks of 32
#define CHUNKB 9216                // 4 kgroups * 144 co * 16 B
#define CHUNKFB 4096               // 4 kgroups * 64 co * 16 B (final layer)
#define WPH_B ((size_t)KG*144*16)  // 543,744 B per hidden layer packed W
#define WPF_B ((size_t)KG*64*16)   // 241,664 B final layer packed W (co padded to 64)

typedef float f32x4 __attribute__((ext_vector_type(4)));
typedef short bf16x8 __attribute__((ext_vector_type(8)));

__device__ __forceinline__ float bf2f(unsigned short u) {
  union { unsigned int i; float f; } v; v.i = ((unsigned int)u) << 16; return v.f;
}
__device__ __forceinline__ unsigned short f2bf(float f) {
  __hip_bfloat16 h = __float2bfloat16(f);
  return __builtin_bit_cast(unsigned short, h);
}
__device__ __forceinline__ void gload_lds16(const void* g, void* l) {
  __builtin_amdgcn_global_load_lds(
      (const __attribute__((address_space(1))) unsigned int*)g,
      (__attribute__((address_space(3))) unsigned int*)l, 16, 0, 0);
}

// ---------------- weight packing ----------------
// K-order is ci-group-major: kgrp = (ci/8)*13 + tap, so all 13 taps of a
// ci-plane are adjacent in K -> activation kx-revisits hit L1/L2.
__global__ void k_pack_h(const float* __restrict__ wr, char* __restrict__ wph) {
  int idx = blockIdx.x * 256 + threadIdx.x;
  if (idx >= 10 * 144 * 144) return;
  int ci = idx % 144; int rem = idx / 144; int co = rem % 144; int layer = rem / 144;
  const float* src = wr + (size_t)((layer * 144 + co) * 144 + ci) * 25;
  unsigned short* dstL = (unsigned short*)(wph + (size_t)layer * WPH_B);
  int cig = ci >> 3, cis = ci & 7;
#pragma unroll
  for (int tap = 0; tap < 13; ++tap) {
    int ky = (tap >= 5) + (tap >= 10);
    int kx = tap - ky * 5;
    dstL[((size_t)(cig * 13 + tap) * 144 + co) * 8 + cis] = f2bf(src[ky * 5 + kx]);
  }
}
__global__ void k_pack_f(const float* __restrict__ wf, char* __restrict__ wpf) {
  int idx = blockIdx.x * 256 + threadIdx.x;
  if (idx >= 49 * 144) return;
  int ci = idx % 144; int co = idx / 144;
  const float* src = wf + (size_t)(co * 144 + ci) * 25;
  unsigned short* dst = (unsigned short*)wpf;
  int cig = ci >> 3, cis = ci & 7;
#pragma unroll
  for (int tap = 0; tap < 13; ++tap) {
    int ky = (tap >= 5) + (tap >= 10);
    int kx = tap - ky * 5;
    dst[((size_t)(cig * 13 + tap) * 64 + co) * 8 + cis] = f2bf(src[ky * 5 + kx]);
  }
}
__global__ void k_biaspad(const float* __restrict__ bf, float* __restrict__ bfp) {
  int i = threadIdx.x;
  bfp[i] = (i < 49) ? bf[i] : -1e30f;
}

// zero only the activation pad cells actually read: rows 0-1 (full) and
// cols {0,1,514,515} of rows 2..257, for both buffers, all 18 planes.
__global__ void k_zeropad(char* __restrict__ actA, char* __restrict__ actB) {
  int i = blockIdx.x * 256 + threadIdx.x;
  if (i >= 2 * 18 * 2064) return;
  int s = i % 2064; int p = i / 2064; int cig = p % 18; int buf = p / 18;
  char* base = (buf ? actB : actA) + (size_t)cig * CGB;
  int row, colpx;
  if (s < 1040) { row = s / 520; colpx = s - row * 520; }
  else { int s2 = s - 1040; row = 2 + (s2 >> 2); int m = s2 & 3; colpx = (m < 2) ? m : (512 + m); }
  uint4 z; z.x = z.y = z.z = z.w = 0u;
  *(uint4*)(base + (size_t)row * ROWB + (size_t)colpx * 16) = z;
}

// ---------------- first layer: 1 -> 144, strictly causal (12 taps) ----------------
__global__ void k_layer0(const float* __restrict__ x, const float* __restrict__ w0,
                         const float* __restrict__ b0, char* __restrict__ act) {
  int i = blockIdx.x * 256 + threadIdx.x;   // one thread per pixel
  int y = i >> 9, xx = i & 511;
  float xv[12];
#pragma unroll
  for (int tp = 0; tp < 12; ++tp) {
    int ky = (tp >= 5) + (tp >= 10);
    int kx = tp - ky * 5;
    int yy = y + ky - 2, xs = xx + kx - 2;
    bool ok = (yy >= 0) && (xs >= 0) && (xs < W);
    xv[tp] = ok ? x[yy * W + xs] : 0.f;
  }
  char* ob = act + (size_t)(y + 2) * ROWB + (size_t)(xx + 2) * XB;
  for (int cg = 0; cg < NCG; ++cg) {
    unsigned int us[4];
#pragma unroll
    for (int h2 = 0; h2 < 4; ++h2) {
      unsigned int lohi = 0;
#pragma unroll
      for (int p = 0; p < 2; ++p) {
        int co = cg * 8 + h2 * 2 + p;
        float a = b0[co];
#pragma unroll
        for (int tp = 0; tp < 12; ++tp) {
          int ky = (tp >= 5) + (tp >= 10);
          int kx = tp - ky * 5;
          a += w0[co * 25 + ky * 5 + kx] * xv[tp];
        }
        a = fmaxf(a, 0.f);
        lohi |= ((unsigned int)f2bf(a)) << (16 * p);
      }
      us[h2] = lohi;
    }
    uint4 v; v.x = us[0]; v.y = us[1]; v.z = us[2]; v.w = us[3];
    *(uint4*)(ob + (size_t)cg * CGB) = v;
  }
}

// ---------------- hidden conv: 144 -> 144, 13 taps, MFMA ----------------
// M-SPLIT WAVE PAIRS: block = 2 waves x 1 row x 64 px. Wave 0 computes co
// tiles 0..4, wave 1 tiles 5..8, sharing one staged weight chunk -> per-CU
// LDS A-read halves vs all-co-per-wave (74 KB/chunk at 16 waves/CU, below the
// 1400cy MFMA floor). B-loads duplicate across the pair (L1/L2-hit). acc is
// <=80 AGPR so 4 waves/SIMD can fit. 8 blocks/CU x 18.4 KB = 147 KB LDS.
__global__ __launch_bounds__(128, 4)
void k_conv(const char* __restrict__ in, char* __restrict__ out,
            const char* __restrict__ wp, const float* __restrict__ bias, int res) {
  __shared__ __align__(16) char lA[2][CHUNKB];
  const int tid = threadIdx.x;
  const int wid = tid >> 6, lane = tid & 63;
  const int col = lane & 15, g = lane >> 4;

  int bid = blockIdx.x;                 // 2048 blocks: 256 rows x 8 x-tiles
  int xcd = bid & 7, idx = bid >> 3;    // idx in [0,256)
  int y = xcd * 32 + (idx >> 3);        // XCD gets contiguous 32-row band
  int x0 = (idx & 7) * 64;

  int pxo[4];
#pragma unroll
  for (int t = 0; t < 4; ++t) pxo[t] = (x0 + 16 * t + col) * XB;
  const char* bbase = in + (size_t)y * ROWB;

  f32x4 acc[5][4];                      // wave0: m 0..4; wave1: m 5..8 (mt<4)
#pragma unroll
  for (int mt = 0; mt < 5; ++mt)
#pragma unroll
    for (int t = 0; t < 4; ++t) acc[mt][t] = (f32x4){0.f, 0.f, 0.f, 0.f};

  bf16x8 bA[4], bB[4];

  // incremental per-lane K state: kg = 4c+g walks tap by +4 (mod 13, cig spill).
  // Pad lanes (kg>=234) walk into adjacent ws regions: finite data x zero weights.
  int tap = g, offc = 0;
  auto bload = [&](bf16x8 (&dst)[4]) __attribute__((always_inline)) {
    int ky = (tap >= 5) + (tap >= 10);
    int kx = tap - ky * 5;
    int off = offc + ky * (int)ROWB + (kx << 4);
#pragma unroll
    for (int t = 0; t < 4; ++t) dst[t] = *(const bf16x8*)(bbase + (size_t)(off + pxo[t]));
    tap += 4; if (tap >= 13) { tap -= 13; offc += (int)CGB; }
  };

  // 9 DMA instr per block split across the pair: wave0 j={0,2,4,6,8}, wave1 {1,3,5,7}
  auto stage = [&](char* ldsn, int c) __attribute__((always_inline)) {
    const char* wsrc = wp + (size_t)c * CHUNKB;
#pragma unroll
    for (int j0 = 0; j0 < 5; ++j0) {
      int j = wid + j0 * 2;
      if (j < 9) gload_lds16(wsrc + (size_t)j * 1024 + (lane << 4), ldsn + j * 1024);
    }
  };

  const int mbase = wid * 5;
  auto domfma = [&](const char* ldsc, bf16x8 (&bcur)[4]) __attribute__((always_inline)) {
    const char* abase = ldsc + ((g * 144 + mbase * 16 + col) << 4);
    __builtin_amdgcn_s_setprio(1);
#pragma unroll
    for (int mt = 0; mt < 5; ++mt) {
      if (mbase + mt < 9) {             // wave-uniform; wave1 skips mt=4
        bf16x8 a = *(const bf16x8*)(abase + mt * 256);
#pragma unroll
        for (int t = 0; t < 4; ++t)
          acc[mt][t] = __builtin_amdgcn_mfma_f32_16x16x32_bf16(a, bcur[t], acc[mt][t], 0, 0, 0);
      }
    }
    __builtin_amdgcn_s_setprio(0);
  };

  // phase c: stage chunk c+1 + prefetch B(c+1), compute chunk c; counted
  // vmcnt(4) retires the stage (4 B prefetch loads stay in flight).
  auto phase = [&](const char* ldsc, char* ldsn, bf16x8 (&bcur)[4], bf16x8 (&bnext)[4],
                   int c) __attribute__((always_inline)) {
    stage(ldsn, c + 1);
    asm volatile("" ::: "memory");      // stage issues precede B prefetch (vmcnt order)
    bload(bnext);                       // chunk c+1
    asm volatile("" ::: "memory");
    domfma(ldsc, bcur);
    asm volatile("s_waitcnt vmcnt(4)" ::: "memory");
    __builtin_amdgcn_s_barrier();
    asm volatile("" ::: "memory");
  };

  // prologue: chunk 0
  stage(&lA[0][0], 0);
  asm volatile("" ::: "memory");
  bload(bA);                            // chunk 0
  asm volatile("s_waitcnt vmcnt(4)" ::: "memory");    // stage(0) landed
  __builtin_amdgcn_s_barrier();
  asm volatile("" ::: "memory");

#pragma unroll 1
  for (int c = 0; c < NCHUNK - 1; c += 2) {   // 29 pairs: phases 0..57
    phase(&lA[0][0], &lA[1][0], bA, bB, c);
    phase(&lA[1][0], &lA[0][0], bB, bA, c + 1);
  }
  domfma(&lA[0][0], bA);                // chunk 58 (staged by phase 57 into buf 0)

  // epilogue: +bias, relu, optional residual (in-place on out), store bf16
  const int sub = (g & 1) * 8;
#pragma unroll
  for (int mt = 0; mt < 5; ++mt) {
    if (mbase + mt < 9) {
      int co0 = (mbase + mt) * 16 + (g << 2);
      f32x4 bv = *(const f32x4*)(bias + co0);
      char* ob = out + (size_t)(co0 >> 3) * CGB + (size_t)(y + 2) * ROWB + sub + 32;
#pragma unroll
      for (int t = 0; t < 4; ++t) {
        char* oa = ob + pxo[t];
        float v0 = fmaxf(acc[mt][t][0] + bv[0], 0.f);
        float v1 = fmaxf(acc[mt][t][1] + bv[1], 0.f);
        float v2 = fmaxf(acc[mt][t][2] + bv[2], 0.f);
        float v3 = fmaxf(acc[mt][t][3] + bv[3], 0.f);
        if (res) {
          uint2 old = *(const uint2*)oa;
          v0 += bf2f((unsigned short)(old.x & 0xffff));
          v1 += bf2f((unsigned short)(old.x >> 16));
          v2 += bf2f((unsigned short)(old.y & 0xffff));
          v3 += bf2f((unsigned short)(old.y >> 16));
        }
        uint2 st;
        st.x = (unsigned int)f2bf(v0) | ((unsigned int)f2bf(v1) << 16);
        st.y = (unsigned int)f2bf(v2) | ((unsigned int)f2bf(v3) << 16);
        *(uint2*)oa = st;
      }
    }
  }
}

// ---------------- final conv (144 -> 49 padded 64) + softmax ----------------
__global__ __launch_bounds__(256, 4)
void k_convf(const char* __restrict__ in, float* __restrict__ probs,
             const char* __restrict__ wp, const float* __restrict__ bfp) {
  __shared__ __align__(16) char lA[2][CHUNKFB];
  const int tid = threadIdx.x;
  const int wid = tid >> 6, lane = tid & 63;
  const int col = lane & 15, g = lane >> 4;

  int bid = blockIdx.x;
  int xcd = bid & 7, idx = bid >> 3;
  int by = xcd * 8 + (idx >> 4), bx = idx & 15;
  int y = by * 4 + wid, x0 = bx * 32;

  int pxo[2];
#pragma unroll
  for (int t = 0; t < 2; ++t) pxo[t] = (x0 + 16 * t + col) * XB;
  const char* bbase = in + (size_t)y * ROWB;

  f32x4 acc[4][2];
#pragma unroll
  for (int m = 0; m < 4; ++m)
#pragma unroll
    for (int t = 0; t < 2; ++t) acc[m][t] = (f32x4){0.f, 0.f, 0.f, 0.f};

  bf16x8 bA[2], bB[2];

  int tap = g, offc = 0;
  auto bload = [&](bf16x8 (&dst)[2]) __attribute__((always_inline)) {
    int ky = (tap >= 5) + (tap >= 10);
    int kx = tap - ky * 5;
    int off = offc + ky * (int)ROWB + (kx << 4);
#pragma unroll
    for (int t = 0; t < 2; ++t) dst[t] = *(const bf16x8*)(bbase + (size_t)(off + pxo[t]));
    tap += 4; if (tap >= 13) { tap -= 13; offc += (int)CGB; }
  };

  auto stage = [&](char* ldsn, int c) __attribute__((always_inline)) {
    if (wid < 4)
      gload_lds16(wp + (size_t)c * CHUNKFB + (size_t)wid * 1024 + (lane << 4),
                  ldsn + wid * 1024);
  };

  auto domfma = [&](const char* ldsc, bf16x8 (&bcur)[2]) __attribute__((always_inline)) {
    const char* abase = ldsc + ((g * 64 + col) << 4);
    __builtin_amdgcn_s_setprio(1);
#pragma unroll
    for (int m = 0; m < 4; ++m) {
      bf16x8 a = *(const bf16x8*)(abase + m * 256);
#pragma unroll
      for (int t = 0; t < 2; ++t)
        acc[m][t] = __builtin_amdgcn_mfma_f32_16x16x32_bf16(a, bcur[t], acc[m][t], 0, 0, 0);
    }
    __builtin_amdgcn_s_setprio(0);
  };

  auto phase = [&](const char* ldsc, char* ldsn, bf16x8 (&bcur)[2], bf16x8 (&bnext)[2],
                   int c) __attribute__((always_inline)) {
    stage(ldsn, c + 1);
    asm volatile("" ::: "memory");
    bload(bnext);
    asm volatile("" ::: "memory");
    domfma(ldsc, bcur);
    asm volatile("s_waitcnt vmcnt(2)" ::: "memory");
    __builtin_amdgcn_s_barrier();
    asm volatile("" ::: "memory");
  };

  stage(&lA[0][0], 0);
  asm volatile("" ::: "memory");
  bload(bA);
  asm volatile("s_waitcnt vmcnt(0)" ::: "memory");
  __builtin_amdgcn_s_barrier();
  asm volatile("" ::: "memory");

#pragma unroll 1
  for (int c = 0; c < NCHUNK - 1; c += 2) {
    phase(&lA[0][0], &lA[1][0], bA, bB, c);
    phase(&lA[1][0], &lA[0][0], bB, bA, c + 1);
  }
  domfma(&lA[0][0], bA);

  // softmax over 49 channels per pixel; lanes (col, g0..3) hold the channel spread
#pragma unroll
  for (int t = 0; t < 2; ++t) {
    float lg[4][4];
    float mx = -1e30f;
#pragma unroll
    for (int m = 0; m < 4; ++m) {
      f32x4 bv = *(const f32x4*)(bfp + m * 16 + (g << 2));
#pragma unroll
      for (int r = 0; r < 4; ++r) {
        lg[m][r] = acc[m][t][r] + bv[r];
        mx = fmaxf(mx, lg[m][r]);
      }
    }
    mx = fmaxf(mx, __shfl_xor(mx, 16));
    mx = fmaxf(mx, __shfl_xor(mx, 32));
    float s = 0.f;
#pragma unroll
    for (int m = 0; m < 4; ++m)
#pragma unroll
      for (int r = 0; r < 4; ++r) {
        lg[m][r] = __expf(lg[m][r] - mx);
        s += lg[m][r];
      }
    s += __shfl_xor(s, 16);
    s += __shfl_xor(s, 32);
    float inv = 1.f / s;
    int xp = x0 + 16 * t + col;
    float* op = probs + (size_t)y * W + xp;
#pragma unroll
    for (int m = 0; m < 4; ++m)
#pragma unroll
      for (int r = 0; r < 4; ++r) {
        int co = m * 16 + (g << 2) + r;
        if (co < 49) op[(size_t)co * (H * W)] = lg[m][r] * inv;
      }
  }
}

// ---------------- importance mask + depth-to-space ----------------
__global__ void k_tmask(const float* __restrict__ x, float* __restrict__ out1) {
  int i = blockIdx.x * 256 + threadIdx.x;   // over 512*1024 outputs per g
  int yy = i >> 10, xx = i & 1023;
  float xv = x[(yy >> 1) * W + (xx >> 1)];
  float tc = floorf((xv + 1.0f) / (float)(2.0 / 47.0) + 1e-5f);
#pragma unroll 4
  for (int g = 0; g < 48; ++g)
    out1[(size_t)g * (512 * 1024) + i] = ((float)g < tc) ? 1.0f : 0.0f;
}

extern "C" void kernel_launch(void* const* d_in, const int* in_sizes, int n_in,
                              void* d_out, int out_size, void* d_ws, size_t ws_size,
                              hipStream_t stream) {
  const float* x  = (const float*)d_in[0];
  const float* w0 = (const float*)d_in[1];
  const float* b0 = (const float*)d_in[2];
  const float* wr = (const float*)d_in[3];
  const float* br = (const float*)d_in[4];
  const float* wf = (const float*)d_in[5];
  const float* bf = (const float*)d_in[6];

  char* ws   = (char*)d_ws;
  char* actA = ws;
  char* actB = ws + ACTB;
  char* wph  = ws + 2 * ACTB;
  char* wpf  = wph + 10 * WPH_B;
  float* bfp = (float*)(wpf + WPF_B);

  // zero weight pad regions (kgrp 234/235, final co 49..63) + bfp tail
  hipMemsetAsync(wph, 0, 10 * WPH_B + WPF_B + 256, stream);
  // zero only the activation pad cells that are read
  k_zeropad<<<(2 * 18 * 2064 + 255) / 256, 256, 0, stream>>>(actA, actB);

  k_pack_h<<<(10 * 144 * 144 + 255) / 256, 256, 0, stream>>>(wr, wph);
  k_pack_f<<<(49 * 144 + 255) / 256, 256, 0, stream>>>(wf, wpf);
  k_biaspad<<<1, 64, 0, stream>>>(bf, bfp);

  k_layer0<<<512, 256, 0, stream>>>(x, w0, b0, actA);

  for (int i = 0; i < 5; ++i) {
    k_conv<<<2048, 128, 0, stream>>>(actA, actB, wph + (size_t)(2 * i) * WPH_B,
                                     br + (2 * i) * 144, 0);
    k_conv<<<2048, 128, 0, stream>>>(actB, actA, wph + (size_t)(2 * i + 1) * WPH_B,
                                     br + (2 * i + 1) * 144, 1);
  }

  float* probs = (float*)d_out;
  k_convf<<<1024, 256, 0, stream>>>(actA, probs, wpf, bfp);
  k_tmask<<<2048, 256, 0, stream>>>(x, probs + (size_t)49 * H * W);
}

// Round 9
// 908.320 us; speedup vs baseline: 1.2260x; 1.2260x over previous
//
#include <hip/hip_runtime.h>
#include <hip/hip_bf16.h>
#include <stdint.h>

#define H 256
#define W 512
#define NCG 18                      // 144/8 channel groups
#define AW 520                      // padded cols: x in [-2, 517]
#define AH 258                      // padded rows: y in [-2, 255]
// fp8 activation planes (conv inputs)
#define XB8 8                       // 8 fp8 per pixel per ci-group
#define ROWF8 (AW*XB8)              // 4160 B
#define CGF8 ((size_t)AH*ROWF8)     // 1,073,280 B per plane
#define ACTF8 ((size_t)NCG*CGF8)    // 19.3 MB per fp8 buffer
// bf16 residual stream h (compact, no halo)
#define CGBR ((size_t)H*W*16)       // 2,097,152 B per plane
#define ACTBF ((size_t)NCG*CGBR)    // 37.7 MB
// fp8 packed weights: K = 13*18=234 kgroups of 8, pad to 240 = 15 chunks of 128
#define NCH8 15
#define CHB8 18432                  // 9 m-tiles * 2048 B per K128 chunk
#define CHBF8 8192                  // 4 m-tiles * 2048 B (final layer)
#define WPH8 ((size_t)NCH8*CHB8)    // 276,480 B per hidden layer
#define WPF8 ((size_t)NCH8*CHBF8)   // 122,880 B final layer

typedef float f32x4 __attribute__((ext_vector_type(4)));
typedef int   i32x4 __attribute__((ext_vector_type(4)));
typedef int   i32x8 __attribute__((ext_vector_type(8)));

__device__ __forceinline__ float bf2f(unsigned short u) {
  union { unsigned int i; float f; } v; v.i = ((unsigned int)u) << 16; return v.f;
}
__device__ __forceinline__ unsigned short f2bf(float f) {
  __hip_bfloat16 h = __float2bfloat16(f);
  return __builtin_bit_cast(unsigned short, h);
}
__device__ __forceinline__ unsigned char f2e4(float f) {
  int v = __builtin_amdgcn_cvt_pk_fp8_f32(f, 0.f, 0, false);
  return (unsigned char)(v & 0xff);
}
__device__ __forceinline__ unsigned int pk4e4(float v0, float v1, float v2, float v3) {
  int p = __builtin_amdgcn_cvt_pk_fp8_f32(v0, v1, 0, false);
  p = __builtin_amdgcn_cvt_pk_fp8_f32(v2, v3, p, true);
  return (unsigned int)p;
}
__device__ __forceinline__ void gload_lds16(const void* g, void* l) {
  __builtin_amdgcn_global_load_lds(
      (const __attribute__((address_space(1))) unsigned int*)g,
      (__attribute__((address_space(3))) unsigned int*)l, 16, 0, 0);
}
// MX-scaled fp8 MFMA, both operands e4m3, all scale bytes = 0x7F (1.0).
__device__ __forceinline__ f32x4 mfma8(i32x8 a, i32x8 b, f32x4 c) {
  return __builtin_amdgcn_mfma_scale_f32_16x16x128_f8f6f4(
      a, b, c, 0, 0, 0, 0x7F7F7F7F, 0, 0x7F7F7F7F);
}

// ---------------- weight packing (fp8) ----------------
// K order ci-group-major: kgrp = (ci/8)*13 + tap. Fragment: lane l holds
// row/co = l&15, k-block = l>>4 (32 k each); byte e of the 32B fragment is
// k = (l>>4)*32 + e, stored as [chunk][m][half e>>4][lane][16B].
__global__ void k_pack_h8(const float* __restrict__ wr, char* __restrict__ wph) {
  int idx = blockIdx.x * 256 + threadIdx.x;
  if (idx >= 10 * 144 * 144) return;
  int ci = idx % 144; int rem = idx / 144; int co = rem % 144; int layer = rem / 144;
  const float* src = wr + (size_t)((layer * 144 + co) * 144 + ci) * 25;
  char* dstL = wph + (size_t)layer * WPH8;
  int m = co >> 4, l_lo = co & 15;
#pragma unroll
  for (int tap = 0; tap < 13; ++tap) {
    int ky = (tap >= 5) + (tap >= 10);
    int kx = tap - ky * 5;
    int k = ((ci >> 3) * 13 + tap) * 8 + (ci & 7);
    int chunk = k >> 7, kr = k & 127, g = kr >> 5, e = kr & 31;
    dstL[(size_t)(chunk * 9 + m) * 2048 + (e >> 4) * 1024 + (g * 16 + l_lo) * 16 + (e & 15)]
        = (char)f2e4(src[ky * 5 + kx]);
  }
}
__global__ void k_pack_f8(const float* __restrict__ wf, char* __restrict__ wpf) {
  int idx = blockIdx.x * 256 + threadIdx.x;
  if (idx >= 49 * 144) return;
  int ci = idx % 144; int co = idx / 144;
  const float* src = wf + (size_t)(co * 144 + ci) * 25;
  int m = co >> 4, l_lo = co & 15;
#pragma unroll
  for (int tap = 0; tap < 13; ++tap) {
    int ky = (tap >= 5) + (tap >= 10);
    int kx = tap - ky * 5;
    int k = ((ci >> 3) * 13 + tap) * 8 + (ci & 7);
    int chunk = k >> 7, kr = k & 127, g = kr >> 5, e = kr & 31;
    wpf[(size_t)(chunk * 4 + m) * 2048 + (e >> 4) * 1024 + (g * 16 + l_lo) * 16 + (e & 15)]
        = (char)f2e4(src[ky * 5 + kx]);
  }
}
__global__ void k_biaspad(const float* __restrict__ bf, float* __restrict__ bfp) {
  int i = threadIdx.x;
  bfp[i] = (i < 49) ? bf[i] : -1e30f;
}

// zero fp8 activation pads: rows 0-1 full + cols {0,1,514,515} rows 2..257,
// for both fp8 buffers, all 18 planes (8B slots).
__global__ void k_zeropad8(char* __restrict__ a8, char* __restrict__ b8) {
  int i = blockIdx.x * 256 + threadIdx.x;
  if (i >= 2 * 18 * 2064) return;
  int s = i % 2064; int p = i / 2064; int cig = p % 18; int buf = p / 18;
  char* base = (buf ? b8 : a8) + (size_t)cig * CGF8;
  int row, colpx;
  if (s < 1040) { row = s / 520; colpx = s - row * 520; }
  else { int s2 = s - 1040; row = 2 + (s2 >> 2); int m = s2 & 3; colpx = (m < 2) ? m : (512 + m); }
  uint2 z; z.x = 0u; z.y = 0u;
  *(uint2*)(base + (size_t)row * ROWF8 + (size_t)colpx * 8) = z;
}

// ---------------- first layer: 1 -> 144, strictly causal (12 taps) ----------------
// Writes h0 to BOTH the bf16 residual stream (compact) and the fp8 conv input.
__global__ void k_layer0(const float* __restrict__ x, const float* __restrict__ w0,
                         const float* __restrict__ b0, char* __restrict__ actbf,
                         char* __restrict__ act8) {
  int i = blockIdx.x * 256 + threadIdx.x;   // one thread per pixel
  int y = i >> 9, xx = i & 511;
  float xv[12];
#pragma unroll
  for (int tp = 0; tp < 12; ++tp) {
    int ky = (tp >= 5) + (tp >= 10);
    int kx = tp - ky * 5;
    int yy = y + ky - 2, xs = xx + kx - 2;
    bool ok = (yy >= 0) && (xs >= 0) && (xs < W);
    xv[tp] = ok ? x[yy * W + xs] : 0.f;
  }
  char* obf = actbf + ((size_t)(y * 512 + xx)) * 16;
  char* ob8 = act8 + (size_t)(y + 2) * ROWF8 + (size_t)(xx + 2) * 8;
  for (int cg = 0; cg < NCG; ++cg) {
    float av[8];
#pragma unroll
    for (int p = 0; p < 8; ++p) {
      int co = cg * 8 + p;
      float a = b0[co];
#pragma unroll
      for (int tp = 0; tp < 12; ++tp) {
        int ky = (tp >= 5) + (tp >= 10);
        int kx = tp - ky * 5;
        a += w0[co * 25 + ky * 5 + kx] * xv[tp];
      }
      av[p] = fmaxf(a, 0.f);
    }
    uint4 vb;
    vb.x = (unsigned int)f2bf(av[0]) | ((unsigned int)f2bf(av[1]) << 16);
    vb.y = (unsigned int)f2bf(av[2]) | ((unsigned int)f2bf(av[3]) << 16);
    vb.z = (unsigned int)f2bf(av[4]) | ((unsigned int)f2bf(av[5]) << 16);
    vb.w = (unsigned int)f2bf(av[6]) | ((unsigned int)f2bf(av[7]) << 16);
    *(uint4*)(obf + (size_t)cg * CGBR) = vb;
    uint2 v8;
    v8.x = pk4e4(av[0], av[1], av[2], av[3]);
    v8.y = pk4e4(av[4], av[5], av[6], av[7]);
    *(uint2*)(ob8 + (size_t)cg * CGF8) = v8;
  }
}

// ---------------- hidden conv: 144 -> 144, 13 taps, MX-fp8 MFMA K=128 ----------------
// r6 structure (4-wave blocks, 1 row x 32px per wave, grid 1024, counted vmcnt,
// per-chunk barrier) at fp8: 15 K-chunks of 128, staged 18.4 KB each, MFMA
// cycles halved vs bf16. res=1 adds the bf16 residual stream exactly and
// rewrites it; fp8 output is a quantized copy for the next conv's input.
__global__ __launch_bounds__(256, 3)
void k_conv(const char* __restrict__ in, char* __restrict__ out8,
            char* __restrict__ resbf, const char* __restrict__ wp,
            const float* __restrict__ bias, int res) {
  __shared__ __align__(16) char lA[2][CHB8];
  const int tid = threadIdx.x;
  const int wid = tid >> 6, lane = tid & 63;
  const int col = lane & 15, g = lane >> 4;

  int bid = blockIdx.x;                 // 1024 blocks
  int xcd = bid & 7, idx = bid >> 3;    // idx in [0,128)
  int by = xcd * 8 + (idx >> 4), bx = idx & 15;   // XCD: contiguous 32-row band
  int y = by * 4 + wid, x0 = bx * 32;

  int pxo[2];
#pragma unroll
  for (int t = 0; t < 2; ++t) pxo[t] = (x0 + 16 * t + col) * XB8;
  const char* bbase = in + (size_t)y * ROWF8;

  f32x4 acc[9][2];
#pragma unroll
  for (int m = 0; m < 9; ++m)
#pragma unroll
    for (int t = 0; t < 2; ++t) acc[m][t] = (f32x4){0.f, 0.f, 0.f, 0.f};

  i32x8 bA[2], bB[2];

  // per-lane K state: base kgroup of this lane's k-block = 16c + 4g,
  // tracked as (cig, tap); advances +16 kgroups per chunk (= tap+3, cig+1).
  int tap = 4 * g, cig = 0;
  auto bload = [&](i32x8 (&dst)[2]) __attribute__((always_inline)) {
#pragma unroll
    for (int s = 0; s < 4; ++s) {
      int ts = tap + s, cs = cig;
      if (ts >= 13) { ts -= 13; cs += 1; }
      if (cs >= 18) { cs = 0; ts = 0; }   // pad kgroups: zero weights, any valid addr
      int ky = (ts >= 5) + (ts >= 10);
      int kx = ts - ky * 5;
      int off = cs * (int)CGF8 + ky * (int)ROWF8 + kx * 8;
#pragma unroll
      for (int t = 0; t < 2; ++t) {
        uint2 u = *(const uint2*)(bbase + (size_t)(off + pxo[t]));
        dst[t][2 * s] = (int)u.x; dst[t][2 * s + 1] = (int)u.y;
      }
    }
    tap += 3; ++cig; if (tap >= 13) { tap -= 13; ++cig; }
  };

  // 18 DMA instr per chunk split over 4 waves (5,5,4,4)
  auto stage = [&](char* ldsn, int c) __attribute__((always_inline)) {
    const char* wsrc = wp + (size_t)c * CHB8;
#pragma unroll
    for (int j0 = 0; j0 < 5; ++j0) {
      int j = wid + j0 * 4;
      if (j < 18) gload_lds16(wsrc + (size_t)j * 1024 + (lane << 4), ldsn + j * 1024);
    }
  };

  auto domfma = [&](const char* ldsc, i32x8 (&b)[2]) __attribute__((always_inline)) {
    __builtin_amdgcn_s_setprio(1);
#pragma unroll
    for (int m = 0; m < 9; ++m) {
      i32x4 lo = *(const i32x4*)(ldsc + m * 2048 + (lane << 4));
      i32x4 hi = *(const i32x4*)(ldsc + m * 2048 + 1024 + (lane << 4));
      i32x8 a = __builtin_shufflevector(lo, hi, 0, 1, 2, 3, 4, 5, 6, 7);
#pragma unroll
      for (int t = 0; t < 2; ++t) acc[m][t] = mfma8(a, b[t], acc[m][t]);
    }
    __builtin_amdgcn_s_setprio(0);
  };

  auto phase = [&](const char* ldsc, char* ldsn, i32x8 (&bcur)[2], i32x8 (&bnext)[2],
                   int c) __attribute__((always_inline)) {
    stage(ldsn, c + 1);
    asm volatile("" ::: "memory");      // stage issues precede B prefetch (vmcnt order)
    bload(bnext);                       // chunk c+1
    asm volatile("" ::: "memory");
    domfma(ldsc, bcur);
    asm volatile("s_waitcnt vmcnt(8)" ::: "memory");  // stage done; 8 B loads in flight
    __builtin_amdgcn_s_barrier();
    asm volatile("" ::: "memory");
  };

  // prologue: chunk 0
  stage(&lA[0][0], 0);
  asm volatile("" ::: "memory");
  bload(bA);                            // chunk 0
  asm volatile("s_waitcnt vmcnt(8)" ::: "memory");
  __builtin_amdgcn_s_barrier();
  asm volatile("" ::: "memory");

#pragma unroll 1
  for (int c = 0; c < NCH8 - 1; c += 2) {   // 7 pairs: chunks 0..13
    phase(&lA[0][0], &lA[1][0], bA, bB, c);
    phase(&lA[1][0], &lA[0][0], bB, bA, c + 1);
  }
  domfma(&lA[0][0], bA);                // chunk 14 (even -> buffer 0)

  // epilogue: +bias, relu, residual in bf16 (exact), fp8 copy for next conv.
  // C/D: col=lane&15(px), row=(lane>>4)*4+r -> co = m*16 + g*4 + r.
#pragma unroll
  for (int m = 0; m < 9; ++m) {
    int co0 = m * 16 + (g << 2);
    f32x4 bv = *(const f32x4*)(bias + co0);
    int plane = co0 >> 3;               // = m*2 + (g>>1)
    int sub = (g & 1);
#pragma unroll
    for (int t = 0; t < 2; ++t) {
      int px = x0 + 16 * t + col;
      float v0 = fmaxf(acc[m][t][0] + bv[0], 0.f);
      float v1 = fmaxf(acc[m][t][1] + bv[1], 0.f);
      float v2 = fmaxf(acc[m][t][2] + bv[2], 0.f);
      float v3 = fmaxf(acc[m][t][3] + bv[3], 0.f);
      if (res) {
        char* rb = resbf + (size_t)plane * CGBR + ((size_t)(y * 512 + px)) * 16 + sub * 8;
        uint2 old = *(const uint2*)rb;
        v0 += bf2f((unsigned short)(old.x & 0xffff));
        v1 += bf2f((unsigned short)(old.x >> 16));
        v2 += bf2f((unsigned short)(old.y & 0xffff));
        v3 += bf2f((unsigned short)(old.y >> 16));
        uint2 st;
        st.x = (unsigned int)f2bf(v0) | ((unsigned int)f2bf(v1) << 16);
        st.y = (unsigned int)f2bf(v2) | ((unsigned int)f2bf(v3) << 16);
        *(uint2*)rb = st;
      }
      char* o8 = out8 + (size_t)plane * CGF8 + (size_t)(y + 2) * ROWF8
               + (size_t)(px + 2) * 8 + sub * 4;
      *(unsigned int*)o8 = pk4e4(v0, v1, v2, v3);
    }
  }
}

// ---------------- final conv (144 -> 49 padded 64, fp8) + softmax ----------------
__global__ __launch_bounds__(256, 4)
void k_convf(const char* __restrict__ in, float* __restrict__ probs,
             const char* __restrict__ wp, const float* __restrict__ bfp) {
  __shared__ __align__(16) char lA[2][CHBF8];
  const int tid = threadIdx.x;
  const int wid = tid >> 6, lane = tid & 63;
  const int col = lane & 15, g = lane >> 4;

  int bid = blockIdx.x;
  int xcd = bid & 7, idx = bid >> 3;
  int by = xcd * 8 + (idx >> 4), bx = idx & 15;
  int y = by * 4 + wid, x0 = bx * 32;

  int pxo[2];
#pragma unroll
  for (int t = 0; t < 2; ++t) pxo[t] = (x0 + 16 * t + col) * XB8;
  const char* bbase = in + (size_t)y * ROWF8;

  f32x4 acc[4][2];
#pragma unroll
  for (int m = 0; m < 4; ++m)
#pragma unroll
    for (int t = 0; t < 2; ++t) acc[m][t] = (f32x4){0.f, 0.f, 0.f, 0.f};

  i32x8 bA[2], bB[2];

  int tap = 4 * g, cig = 0;
  auto bload = [&](i32x8 (&dst)[2]) __attribute__((always_inline)) {
#pragma unroll
    for (int s = 0; s < 4; ++s) {
      int ts = tap + s, cs = cig;
      if (ts >= 13) { ts -= 13; cs += 1; }
      if (cs >= 18) { cs = 0; ts = 0; }
      int ky = (ts >= 5) + (ts >= 10);
      int kx = ts - ky * 5;
      int off = cs * (int)CGF8 + ky * (int)ROWF8 + kx * 8;
#pragma unroll
      for (int t = 0; t < 2; ++t) {
        uint2 u = *(const uint2*)(bbase + (size_t)(off + pxo[t]));
        dst[t][2 * s] = (int)u.x; dst[t][2 * s + 1] = (int)u.y;
      }
    }
    tap += 3; ++cig; if (tap >= 13) { tap -= 13; ++cig; }
  };

  auto stage = [&](char* ldsn, int c) __attribute__((always_inline)) {
    const char* wsrc = wp + (size_t)c * CHBF8;
#pragma unroll
    for (int j0 = 0; j0 < 2; ++j0) {
      int j = wid + j0 * 4;
      gload_lds16(wsrc + (size_t)j * 1024 + (lane << 4), ldsn + j * 1024);
    }
  };

  auto domfma = [&](const char* ldsc, i32x8 (&b)[2]) __attribute__((always_inline)) {
    __builtin_amdgcn_s_setprio(1);
#pragma unroll
    for (int m = 0; m < 4; ++m) {
      i32x4 lo = *(const i32x4*)(ldsc + m * 2048 + (lane << 4));
      i32x4 hi = *(const i32x4*)(ldsc + m * 2048 + 1024 + (lane << 4));
      i32x8 a = __builtin_shufflevector(lo, hi, 0, 1, 2, 3, 4, 5, 6, 7);
#pragma unroll
      for (int t = 0; t < 2; ++t) acc[m][t] = mfma8(a, b[t], acc[m][t]);
    }
    __builtin_amdgcn_s_setprio(0);
  };

  auto phase = [&](const char* ldsc, char* ldsn, i32x8 (&bcur)[2], i32x8 (&bnext)[2],
                   int c) __attribute__((always_inline)) {
    stage(ldsn, c + 1);
    asm volatile("" ::: "memory");
    bload(bnext);
    asm volatile("" ::: "memory");
    domfma(ldsc, bcur);
    asm volatile("s_waitcnt vmcnt(8)" ::: "memory");
    __builtin_amdgcn_s_barrier();
    asm volatile("" ::: "memory");
  };

  stage(&lA[0][0], 0);
  asm volatile("" ::: "memory");
  bload(bA);
  asm volatile("s_waitcnt vmcnt(8)" ::: "memory");
  __builtin_amdgcn_s_barrier();
  asm volatile("" ::: "memory");

#pragma unroll 1
  for (int c = 0; c < NCH8 - 1; c += 2) {
    phase(&lA[0][0], &lA[1][0], bA, bB, c);
    phase(&lA[1][0], &lA[0][0], bB, bA, c + 1);
  }
  domfma(&lA[0][0], bA);

  // softmax over 49 channels per pixel; lanes (col, g0..3) hold the channel spread
#pragma unroll
  for (int t = 0; t < 2; ++t) {
    float lg[4][4];
    float mx = -1e30f;
#pragma unroll
    for (int m = 0; m < 4; ++m) {
      f32x4 bv = *(const f32x4*)(bfp + m * 16 + (g << 2));
#pragma unroll
      for (int r = 0; r < 4; ++r) {
        lg[m][r] = acc[m][t][r] + bv[r];
        mx = fmaxf(mx, lg[m][r]);
      }
    }
    mx = fmaxf(mx, __shfl_xor(mx, 16));
    mx = fmaxf(mx, __shfl_xor(mx, 32));
    float s = 0.f;
#pragma unroll
    for (int m = 0; m < 4; ++m)
#pragma unroll
      for (int r = 0; r < 4; ++r) {
        lg[m][r] = __expf(lg[m][r] - mx);
        s += lg[m][r];
      }
    s += __shfl_xor(s, 16);
    s += __shfl_xor(s, 32);
    float inv = 1.f / s;
    int xp = x0 + 16 * t + col;
    float* op = probs + (size_t)y * W + xp;
#pragma unroll
    for (int m = 0; m < 4; ++m)
#pragma unroll
      for (int r = 0; r < 4; ++r) {
        int co = m * 16 + (g << 2) + r;
        if (co < 49) op[(size_t)co * (H * W)] = lg[m][r] * inv;
      }
  }
}

// ---------------- importance mask + depth-to-space ----------------
__global__ void k_tmask(const float* __restrict__ x, float* __restrict__ out1) {
  int i = blockIdx.x * 256 + threadIdx.x;   // over 512*1024 outputs per g
  int yy = i >> 10, xx = i & 1023;
  float xv = x[(yy >> 1) * W + (xx >> 1)];
  float tc = floorf((xv + 1.0f) / (float)(2.0 / 47.0) + 1e-5f);
#pragma unroll 4
  for (int g = 0; g < 48; ++g)
    out1[(size_t)g * (512 * 1024) + i] = ((float)g < tc) ? 1.0f : 0.0f;
}

extern "C" void kernel_launch(void* const* d_in, const int* in_sizes, int n_in,
                              void* d_out, int out_size, void* d_ws, size_t ws_size,
                              hipStream_t stream) {
  const float* x  = (const float*)d_in[0];
  const float* w0 = (const float*)d_in[1];
  const float* b0 = (const float*)d_in[2];
  const float* wr = (const float*)d_in[3];
  const float* br = (const float*)d_in[4];
  const float* wf = (const float*)d_in[5];
  const float* bf = (const float*)d_in[6];

  char* ws    = (char*)d_ws;
  char* a8    = ws;                     // fp8 h stream
  char* b8    = ws + ACTF8;             // fp8 y stream
  char* hbf   = ws + 2 * ACTF8;         // bf16 residual stream h
  char* wph8  = hbf + ACTBF;
  char* wpf8  = wph8 + 10 * WPH8;
  float* bfp  = (float*)(wpf8 + WPF8);

  // zero fp8 weight pad regions (kgroups 234-239, final co 49..63) + bfp tail
  hipMemsetAsync(wph8, 0, 10 * WPH8 + WPF8 + 256, stream);
  // zero fp8 activation pads (bf16 stream has no halo)
  k_zeropad8<<<(2 * 18 * 2064 + 255) / 256, 256, 0, stream>>>(a8, b8);

  k_pack_h8<<<(10 * 144 * 144 + 255) / 256, 256, 0, stream>>>(wr, wph8);
  k_pack_f8<<<(49 * 144 + 255) / 256, 256, 0, stream>>>(wf, wpf8);
  k_biaspad<<<1, 64, 0, stream>>>(bf, bfp);

  k_layer0<<<512, 256, 0, stream>>>(x, w0, b0, hbf, a8);

  for (int i = 0; i < 5; ++i) {
    // y = relu(conv(h)): fp8 only
    k_conv<<<1024, 256, 0, stream>>>(a8, b8, hbf, wph8 + (size_t)(2 * i) * WPH8,
                                     br + (2 * i) * 144, 0);
    // h = h + relu(conv(y)): bf16 residual updated exactly + fp8 copy
    k_conv<<<1024, 256, 0, stream>>>(b8, a8, hbf, wph8 + (size_t)(2 * i + 1) * WPH8,
                                     br + (2 * i + 1) * 144, 1);
  }

  float* probs = (float*)d_out;
  k_convf<<<1024, 256, 0, stream>>>(a8, probs, wpf8, bfp);
  k_tmask<<<2048, 256, 0, stream>>>(x, probs + (size_t)49 * H * W);
}